// Round 1
// baseline (138.187 us; speedup 1.0000x reference)
//
#include <hip/hip_runtime.h>
#include <math.h>

#define N      512
#define DIMC   128
#define HEADS  4
#define DH     32
#define INDC   5
#define SCALE  0.1767766952966369f   // 32^-0.5

// ---------------- Kernel A: qkv = w_qkv (384x128) @ x (128x512) ----------------
// 8 output rows per block; x read coalesced, weights staged in LDS.
__global__ __launch_bounds__(256) void qkv_kernel(const float* __restrict__ w,
                                                  const float* __restrict__ x,
                                                  float* __restrict__ qkv) {
    __shared__ float ws[8 * DIMC];
    const int o0 = blockIdx.x * 8;
    const int t  = threadIdx.x;
    for (int idx = t; idx < 8 * DIMC; idx += 256) ws[idx] = w[o0 * DIMC + idx];
    __syncthreads();
    for (int i = t; i < N; i += 256) {
        float acc[8] = {0.f, 0.f, 0.f, 0.f, 0.f, 0.f, 0.f, 0.f};
        for (int c = 0; c < DIMC; ++c) {
            const float xv = x[c * N + i];
#pragma unroll
            for (int r = 0; r < 8; ++r) acc[r] = fmaf(ws[r * DIMC + c], xv, acc[r]);
        }
#pragma unroll
        for (int r = 0; r < 8; ++r) qkv[(o0 + r) * N + i] = acc[r];
    }
}

// ------------- Kernel A2: Aq[h,c,i], Ak[h,c,j], M[h,c,c'] (one block/head) -------------
__global__ __launch_bounds__(256) void proj_ind_kernel(const float* __restrict__ qkv,
                                                       const float* __restrict__ w_ind,
                                                       float* __restrict__ Aq,
                                                       float* __restrict__ Ak,
                                                       float* __restrict__ Mh) {
    const int h = blockIdx.x;
    const int t = threadIdx.x;
    __shared__ float wq[DH * INDC], wk[DH * INDC];
    if (t < DH * INDC) {
        wq[t] = w_ind[(h * DH) * INDC + t];            // ind_q weights: rows [0,128)
        wk[t] = w_ind[(DIMC + h * DH) * INDC + t];     // ind_k weights: rows [128,256)
    }
    __syncthreads();
    if (t < INDC * INDC) {
        const int c = t / INDC, cc = t % INDC;
        float acc = 0.f;
        for (int d = 0; d < DH; ++d) acc = fmaf(wq[d * INDC + c], wk[d * INDC + cc], acc);
        Mh[h * INDC * INDC + t] = acc;
    }
    const float* q = qkv;
    const float* k = qkv + DIMC * N;
    for (int i = t; i < N; i += 256) {
        float accq[INDC] = {0.f, 0.f, 0.f, 0.f, 0.f};
        float acck[INDC] = {0.f, 0.f, 0.f, 0.f, 0.f};
        for (int d = 0; d < DH; ++d) {
            const float qd = q[(h * DH + d) * N + i];
            const float kd = k[(h * DH + d) * N + i];
#pragma unroll
            for (int c = 0; c < INDC; ++c) {
                accq[c] = fmaf(qd, wk[d * INDC + c], accq[c]);  // Aq uses W_ind_k
                acck[c] = fmaf(kd, wq[d * INDC + c], acck[c]);  // Ak uses W_ind_q
            }
        }
#pragma unroll
        for (int c = 0; c < INDC; ++c) {
            Aq[(h * INDC + c) * N + i] = accq[c];
            Ak[(h * INDC + c) * N + i] = acck[c];
        }
    }
}

// ------------- Kernel B: fused sim + softmax + PV, one block per (i, h) -------------
__global__ __launch_bounds__(256) void attn_kernel(const float* __restrict__ qkv,
                                                   const float* __restrict__ ind,
                                                   const float* __restrict__ Aq,
                                                   const float* __restrict__ Ak,
                                                   const float* __restrict__ Mh,
                                                   float* __restrict__ att_out) {
    const int i    = blockIdx.x;
    const int h    = blockIdx.y;
    const int t    = threadIdx.x;
    const int lane = t & 63;
    const int wave = t >> 6;

    __shared__ float qs[DH];
    __shared__ float aqs[INDC];
    __shared__ float ms[INDC * INDC];
    __shared__ float ps[N];
    __shared__ float red[4];

    const float* q = qkv;
    const float* k = qkv + DIMC * N;
    const float* v = qkv + 2 * DIMC * N;

    if (t < DH) qs[t] = q[(h * DH + t) * N + i];
    else if (t >= 64 && t < 64 + INDC) aqs[t - 64] = Aq[(h * INDC + (t - 64)) * N + i];
    else if (t >= 128 && t < 128 + INDC * INDC) ms[t - 128] = Mh[h * INDC * INDC + (t - 128)];
    __syncthreads();

    float sim[2];
#pragma unroll
    for (int s = 0; s < 2; ++s) {
        const int j = t + s * 256;
        float ic[INDC];
#pragma unroll
        for (int c = 0; c < INDC; ++c) ic[c] = ind[(c * N + i) * N + j];
        float qk = 0.f;
#pragma unroll
        for (int d = 0; d < DH; ++d) qk = fmaf(qs[d], k[(h * DH + d) * N + j], qk);
        float lin = 0.f;
#pragma unroll
        for (int c = 0; c < INDC; ++c)
            lin = fmaf(aqs[c] + Ak[(h * INDC + c) * N + j], ic[c], lin);
        float quad = 0.f;
#pragma unroll
        for (int c = 0; c < INDC; ++c) {
            float tc = 0.f;
#pragma unroll
            for (int cc = 0; cc < INDC; ++cc) tc = fmaf(ms[c * INDC + cc], ic[cc], tc);
            quad = fmaf(ic[c], tc, quad);
        }
        sim[s] = SCALE * (qk + lin + quad);
    }

    // ---- block softmax over 512 ----
    float m = fmaxf(sim[0], sim[1]);
#pragma unroll
    for (int off = 32; off; off >>= 1) m = fmaxf(m, __shfl_down(m, off, 64));
    if (lane == 0) red[wave] = m;
    __syncthreads();
    m = fmaxf(fmaxf(red[0], red[1]), fmaxf(red[2], red[3]));
    const float e0 = __expf(sim[0] - m);
    const float e1 = __expf(sim[1] - m);
    float sum = e0 + e1;
#pragma unroll
    for (int off = 32; off; off >>= 1) sum += __shfl_down(sum, off, 64);
    __syncthreads();   // all reads of red (max) done before rewrite
    if (lane == 0) red[wave] = sum;
    __syncthreads();
    sum = (red[0] + red[1]) + (red[2] + red[3]);
    const float rs = 1.f / sum;
    ps[t]       = e0 * rs;
    ps[t + 256] = e1 * rs;
    __syncthreads();

    // ---- PV: wave w handles d in [w*8, w*8+8) ----
#pragma unroll
    for (int dd = 0; dd < 8; ++dd) {
        const int d = wave * 8 + dd;
        const float* vr = v + (h * DH + d) * N;
        float acc = 0.f;
#pragma unroll
        for (int s = 0; s < 8; ++s) acc = fmaf(ps[lane + 64 * s], vr[lane + 64 * s], acc);
#pragma unroll
        for (int off = 32; off; off >>= 1) acc += __shfl_down(acc, off, 64);
        if (lane == 0) att_out[(h * DH + d) * N + i] = acc;
    }
}

// ------------- Kernel C: out = w_out (128x128) @ att (128x512) + b_out -------------
__global__ __launch_bounds__(256) void outproj_kernel(const float* __restrict__ w,
                                                      const float* __restrict__ b,
                                                      const float* __restrict__ att,
                                                      float* __restrict__ out) {
    __shared__ float ws[8 * DIMC];
    const int o0 = blockIdx.x * 8;
    const int t  = threadIdx.x;
    for (int idx = t; idx < 8 * DIMC; idx += 256) ws[idx] = w[o0 * DIMC + idx];
    __syncthreads();
    for (int i = t; i < N; i += 256) {
        float acc[8] = {0.f, 0.f, 0.f, 0.f, 0.f, 0.f, 0.f, 0.f};
        for (int c = 0; c < DIMC; ++c) {
            const float av = att[c * N + i];
#pragma unroll
            for (int r = 0; r < 8; ++r) acc[r] = fmaf(ws[r * DIMC + c], av, acc[r]);
        }
#pragma unroll
        for (int r = 0; r < 8; ++r) out[(o0 + r) * N + i] = acc[r] + b[o0 + r];
    }
}

extern "C" void kernel_launch(void* const* d_in, const int* in_sizes, int n_in,
                              void* d_out, int out_size, void* d_ws, size_t ws_size,
                              hipStream_t stream) {
    const float* x         = (const float*)d_in[0];  // (1,128,512)
    const float* indicator = (const float*)d_in[1];  // (1,5,512,512)
    const float* w_qkv     = (const float*)d_in[2];  // (384,128)
    const float* w_ind     = (const float*)d_in[3];  // (256,5)
    const float* w_out     = (const float*)d_in[4];  // (128,128)
    const float* b_out     = (const float*)d_in[5];  // (128,)
    float* out = (float*)d_out;                      // (1,128,512)

    float* qkv = (float*)d_ws;                 // 384*512
    float* Aq  = qkv + 3 * DIMC * N;           // 4*5*512
    float* Ak  = Aq + HEADS * INDC * N;        // 4*5*512
    float* Mh  = Ak + HEADS * INDC * N;        // 4*25 (padded to 128)
    float* att = Mh + 128;                     // 128*512

    qkv_kernel<<<(3 * DIMC) / 8, 256, 0, stream>>>(w_qkv, x, qkv);
    proj_ind_kernel<<<HEADS, 256, 0, stream>>>(qkv, w_ind, Aq, Ak, Mh);
    attn_kernel<<<dim3(N, HEADS), 256, 0, stream>>>(qkv, indicator, Aq, Ak, Mh, att);
    outproj_kernel<<<DIMC / 8, 256, 0, stream>>>(w_out, b_out, att, out);
}

// Round 2
// 118.510 us; speedup vs baseline: 1.1660x; 1.1660x over previous
//
#include <hip/hip_runtime.h>
#include <math.h>

#define N      512
#define DIMC   128
#define HEADS  4
#define DH     32
#define INDC   5
#define SCALE  0.1767766952966369f   // 32^-0.5

// Virtual output rows of the fused pre-GEMM: all are (row_weights) @ x
//   rows [0,384)   : qkv        (q rows 0..127, k 128..255, v 256..383)
//   rows [384,404) : Aq[(h*5+c)] with composite weight  Wq_rows . W_ind_k
//   rows [404,424) : Ak[(h*5+c)] with composite weight  Wk_rows . W_ind_q
#define QKV_ROWS 384
#define AQ_BASE  384
#define AK_BASE  404
#define TOT_ROWS 424

// ---------------- Kernel 1: fused pre-GEMM (qkv + Aq + Ak + M) ----------------
__global__ __launch_bounds__(256) void pre_kernel(const float* __restrict__ w_qkv,
                                                  const float* __restrict__ w_ind,
                                                  const float* __restrict__ x,
                                                  float* __restrict__ rows_out,
                                                  float* __restrict__ Mh) {
    const int bx = blockIdx.x;
    const int t  = threadIdx.x;
    if (bx == TOT_ROWS / 4) {
        // M[h,c,cc] = sum_d w_ind_q[h,d,c] * w_ind_k[h,d,cc]  (weights only)
        if (blockIdx.y != 0) return;
        if (t < HEADS * INDC * INDC) {
            const int h = t / 25, c = (t / 5) % 5, cc = t % 5;
            float acc = 0.f;
            for (int d = 0; d < DH; ++d)
                acc = fmaf(w_ind[(h * DH + d) * INDC + c],
                           w_ind[(DIMC + h * DH + d) * INDC + cc], acc);
            Mh[t] = acc;
        }
        return;
    }
    __shared__ float ws[4 * DIMC];
    const int o0 = bx * 4;
    // Build the 4 effective weight rows in LDS.
    for (int idx = t; idx < 4 * DIMC; idx += 256) {
        const int rl = idx >> 7, m = idx & 127;
        const int row = o0 + rl;
        float val;
        if (row < QKV_ROWS) {
            val = w_qkv[row * DIMC + m];
        } else if (row < AK_BASE) {              // Aq composite: q-rows . W_ind_k
            const int r = row - AQ_BASE, h = r / INDC, c = r % INDC;
            float acc = 0.f;
            for (int d = 0; d < DH; ++d)
                acc = fmaf(w_qkv[(h * DH + d) * DIMC + m],
                           w_ind[(DIMC + h * DH + d) * INDC + c], acc);
            val = acc;
        } else {                                  // Ak composite: k-rows . W_ind_q
            const int r = row - AK_BASE, h = r / INDC, c = r % INDC;
            float acc = 0.f;
            for (int d = 0; d < DH; ++d)
                acc = fmaf(w_qkv[(DIMC + h * DH + d) * DIMC + m],
                           w_ind[(h * DH + d) * INDC + c], acc);
            val = acc;
        }
        ws[idx] = val;
    }
    __syncthreads();
    const int i = blockIdx.y * 256 + t;
    float acc[4] = {0.f, 0.f, 0.f, 0.f};
#pragma unroll 4
    for (int c = 0; c < DIMC; ++c) {
        const float xv = x[c * N + i];
#pragma unroll
        for (int r = 0; r < 4; ++r) acc[r] = fmaf(ws[r * DIMC + c], xv, acc[r]);
    }
#pragma unroll
    for (int r = 0; r < 4; ++r) rows_out[(o0 + r) * N + i] = acc[r];
}

// ------------- Kernel 2: fused sim + softmax + PV, one block per (i, h) -------------
__global__ __launch_bounds__(256) void attn_kernel(const float* __restrict__ rows,
                                                   const float* __restrict__ ind,
                                                   const float* __restrict__ Mh,
                                                   float* __restrict__ att_out) {
    const int i    = blockIdx.x;
    const int h    = blockIdx.y;
    const int t    = threadIdx.x;
    const int lane = t & 63;
    const int wave = t >> 6;

    __shared__ float qs[DH];
    __shared__ float aqs[INDC];
    __shared__ float ms[INDC * INDC];
    __shared__ float ps[N];
    __shared__ float red[4];

    const float* q  = rows;
    const float* k  = rows + DIMC * N;
    const float* v  = rows + 2 * DIMC * N;
    const float* Aq = rows + 3 * DIMC * N;
    const float* Ak = Aq + HEADS * INDC * N;

    if (t < DH) qs[t] = q[(h * DH + t) * N + i];
    else if (t >= 64 && t < 64 + INDC) aqs[t - 64] = Aq[(h * INDC + (t - 64)) * N + i];
    else if (t >= 128 && t < 128 + INDC * INDC) ms[t - 128] = Mh[h * 25 + (t - 128)];
    __syncthreads();

    // thread t owns j-pair (2t, 2t+1) -> all row accesses are float2 at index t
    float2 ic[INDC];
#pragma unroll
    for (int c = 0; c < INDC; ++c)
        ic[c] = ((const float2*)(ind + (c * N + i) * N))[t];

    float2 qk = {0.f, 0.f};
#pragma unroll
    for (int d = 0; d < DH; ++d) {
        const float2 kv = ((const float2*)(k + (h * DH + d) * N))[t];
        qk.x = fmaf(qs[d], kv.x, qk.x);
        qk.y = fmaf(qs[d], kv.y, qk.y);
    }
    float2 lin = {0.f, 0.f};
#pragma unroll
    for (int c = 0; c < INDC; ++c) {
        const float2 akv = ((const float2*)(Ak + (h * INDC + c) * N))[t];
        lin.x = fmaf(aqs[c] + akv.x, ic[c].x, lin.x);
        lin.y = fmaf(aqs[c] + akv.y, ic[c].y, lin.y);
    }
    float2 quad = {0.f, 0.f};
#pragma unroll
    for (int c = 0; c < INDC; ++c) {
        float2 tc = {0.f, 0.f};
#pragma unroll
        for (int cc = 0; cc < INDC; ++cc) {
            const float mv = ms[c * INDC + cc];
            tc.x = fmaf(mv, ic[cc].x, tc.x);
            tc.y = fmaf(mv, ic[cc].y, tc.y);
        }
        quad.x = fmaf(ic[c].x, tc.x, quad.x);
        quad.y = fmaf(ic[c].y, tc.y, quad.y);
    }
    const float s0 = SCALE * (qk.x + lin.x + quad.x);
    const float s1 = SCALE * (qk.y + lin.y + quad.y);

    // ---- block softmax over 512 ----
    float m = fmaxf(s0, s1);
#pragma unroll
    for (int off = 32; off; off >>= 1) m = fmaxf(m, __shfl_down(m, off, 64));
    if (lane == 0) red[wave] = m;
    __syncthreads();
    m = fmaxf(fmaxf(red[0], red[1]), fmaxf(red[2], red[3]));
    const float e0 = __expf(s0 - m);
    const float e1 = __expf(s1 - m);
    float sum = e0 + e1;
#pragma unroll
    for (int off = 32; off; off >>= 1) sum += __shfl_down(sum, off, 64);
    __syncthreads();   // all reads of red (max) done before rewrite
    if (lane == 0) red[wave] = sum;
    __syncthreads();
    sum = (red[0] + red[1]) + (red[2] + red[3]);
    const float rs = 1.f / sum;
    ((float2*)ps)[t] = make_float2(e0 * rs, e1 * rs);
    __syncthreads();

    // ---- PV: wave w handles d in [w*8, w*8+8), lanes split j in float2 pairs ----
    const float2* ps2 = (const float2*)ps;
#pragma unroll
    for (int dd = 0; dd < 8; ++dd) {
        const int d = wave * 8 + dd;
        const float2* vr = (const float2*)(v + (h * DH + d) * N);
        float acc = 0.f;
#pragma unroll
        for (int s = 0; s < 4; ++s) {
            const float2 p  = ps2[lane + 64 * s];
            const float2 vv = vr[lane + 64 * s];
            acc = fmaf(p.x, vv.x, fmaf(p.y, vv.y, acc));
        }
#pragma unroll
        for (int off = 32; off; off >>= 1) acc += __shfl_down(acc, off, 64);
        if (lane == 0) att_out[(h * DH + d) * N + i] = acc;
    }
}

// ------------- Kernel 3: out = w_out (128x128) @ att (128x512) + b_out -------------
__global__ __launch_bounds__(256) void outproj_kernel(const float* __restrict__ w,
                                                      const float* __restrict__ b,
                                                      const float* __restrict__ att,
                                                      float* __restrict__ out) {
    __shared__ float ws[4 * DIMC];
    const int o0 = blockIdx.x * 4;
    const int t  = threadIdx.x;
    for (int idx = t; idx < 4 * DIMC; idx += 256) ws[idx] = w[o0 * DIMC + idx];
    __syncthreads();
    const int i = blockIdx.y * 256 + t;
    float acc[4] = {0.f, 0.f, 0.f, 0.f};
#pragma unroll 4
    for (int c = 0; c < DIMC; ++c) {
        const float av = att[c * N + i];
#pragma unroll
        for (int r = 0; r < 4; ++r) acc[r] = fmaf(ws[r * DIMC + c], av, acc[r]);
    }
#pragma unroll
    for (int r = 0; r < 4; ++r) out[(o0 + r) * N + i] = acc[r] + b[o0 + r];
}

extern "C" void kernel_launch(void* const* d_in, const int* in_sizes, int n_in,
                              void* d_out, int out_size, void* d_ws, size_t ws_size,
                              hipStream_t stream) {
    const float* x         = (const float*)d_in[0];  // (1,128,512)
    const float* indicator = (const float*)d_in[1];  // (1,5,512,512)
    const float* w_qkv     = (const float*)d_in[2];  // (384,128)
    const float* w_ind     = (const float*)d_in[3];  // (256,5)
    const float* w_out     = (const float*)d_in[4];  // (128,128)
    const float* b_out     = (const float*)d_in[5];  // (128,)
    float* out = (float*)d_out;                      // (1,128,512)

    float* rows = (float*)d_ws;                 // 424 * 512  (qkv | Aq | Ak)
    float* Mh   = rows + TOT_ROWS * N;          // 4*25 (padded to 128)
    float* att  = Mh + 128;                     // 128*512

    pre_kernel<<<dim3(TOT_ROWS / 4 + 1, 2), 256, 0, stream>>>(w_qkv, w_ind, x, rows, Mh);
    attn_kernel<<<dim3(N, HEADS), 256, 0, stream>>>(rows, indicator, Mh, att);
    outproj_kernel<<<dim3(DIMC / 4, 2), 256, 0, stream>>>(w_out, b_out, att, out);
}

// Round 3
// 117.382 us; speedup vs baseline: 1.1772x; 1.0096x over previous
//
#include <hip/hip_runtime.h>
#include <math.h>

#define N      512
#define DIMC   128
#define HEADS  4
#define DH     32
#define INDC   5
#define SCALE  0.1767766952966369f   // 32^-0.5

// Virtual output rows of the fused pre-GEMM: all are (row_weights) @ x
//   rows [0,384)   : qkv   (q rows 0..127, k 128..255, v 256..383)
//   rows [384,404) : Aq[(h*5+c)]  composite weight  Wq_rows . W_ind_k
//   rows [404,424) : Ak[(h*5+c)]  composite weight  Wk_rows . W_ind_q
#define QKV_ROWS 384
#define AQ_BASE  384
#define AK_BASE  404
#define TOT_ROWS 424
#define NROW_BLK (TOT_ROWS / 4)   // 106

// ws float offsets
#define ROWS_F   0
#define MHS_F    (TOT_ROWS * N)          // 64 floats: MhS[4][16] symmetrized
#define WOUTT_F  (MHS_F + 64)            // 16384 floats: w_out transposed

// ---------------- Kernel 1: fused pre-GEMM + MhS + w_out transpose ----------------
__global__ __launch_bounds__(256) void pre_kernel(const float* __restrict__ w_qkv,
                                                  const float* __restrict__ w_ind,
                                                  const float* __restrict__ x,
                                                  const float* __restrict__ w_out,
                                                  float* __restrict__ ws) {
    const int bx = blockIdx.x;
    const int t  = threadIdx.x;
    float* rows   = ws + ROWS_F;
    float* MhS    = ws + MHS_F;
    float* w_outT = ws + WOUTT_F;

    if (bx == NROW_BLK) {
        // --- M[h,c,cc] = sum_d w_ind_q[h,d,c] * w_ind_k[h,d,cc], then symmetrize ---
        __shared__ float mraw[HEADS * INDC * INDC];
        if (t < HEADS * INDC * INDC) {
            const int h = t / 25, c = (t / 5) % 5, cc = t % 5;
            float acc = 0.f;
            for (int d = 0; d < DH; ++d)
                acc = fmaf(w_ind[(h * DH + d) * INDC + c],
                           w_ind[(DIMC + h * DH + d) * INDC + cc], acc);
            mraw[t] = acc;
        }
        __syncthreads();
        if (t < 64) {
            const int h = t >> 4, idx = t & 15;
            const int PC[10]  = {0, 0, 0, 0, 1, 1, 1, 2, 2, 3};
            const int PCC[10] = {1, 2, 3, 4, 2, 3, 4, 3, 4, 4};
            float s = 0.f;
            if (idx < 5) {
                s = mraw[h * 25 + idx * 5 + idx];
            } else if (idx < 15) {
                const int c = PC[idx - 5], cc = PCC[idx - 5];
                s = mraw[h * 25 + c * 5 + cc] + mraw[h * 25 + cc * 5 + c];
            }
            MhS[h * 16 + idx] = s;
        }
        // --- transpose w_out (128x128) so the fused outproj reads coalesced ---
        for (int idx = t; idx < DIMC * DIMC; idx += 256) {
            const int o = idx >> 7, c = idx & 127;
            w_outT[c * DIMC + o] = w_out[idx];
        }
        return;
    }

    // --- 4 virtual rows per block, c-major float4 layout in LDS ---
    __shared__ float ws2[4 * DIMC];   // ws2[c*4 + r]
    const int o0 = bx * 4;
    for (int idx = t; idx < 4 * DIMC; idx += 256) {
        const int r = idx & 3, m = idx >> 2;
        const int row = o0 + r;
        float val;
        if (row < QKV_ROWS) {
            val = w_qkv[row * DIMC + m];
        } else if (row < AK_BASE) {              // Aq composite: q-rows . W_ind_k
            const int rr = row - AQ_BASE, h = rr / INDC, c = rr % INDC;
            float acc = 0.f;
            for (int d = 0; d < DH; ++d)
                acc = fmaf(w_qkv[(h * DH + d) * DIMC + m],
                           w_ind[(DIMC + h * DH + d) * INDC + c], acc);
            val = acc;
        } else {                                  // Ak composite: k-rows . W_ind_q
            const int rr = row - AK_BASE, h = rr / INDC, c = rr % INDC;
            float acc = 0.f;
            for (int d = 0; d < DH; ++d)
                acc = fmaf(w_qkv[(DIMC + h * DH + d) * DIMC + m],
                           w_ind[(h * DH + d) * INDC + c], acc);
            val = acc;
        }
        ws2[m * 4 + r] = val;
    }
    __syncthreads();

    const float2* x2 = (const float2*)x;      // thread t owns i-pair (2t, 2t+1)
    float2 acc[4] = {{0.f,0.f},{0.f,0.f},{0.f,0.f},{0.f,0.f}};
#pragma unroll 8
    for (int c = 0; c < DIMC; ++c) {
        const float2 xv = x2[c * 256 + t];
        const float4 wv = *(const float4*)(ws2 + c * 4);
        acc[0].x = fmaf(wv.x, xv.x, acc[0].x); acc[0].y = fmaf(wv.x, xv.y, acc[0].y);
        acc[1].x = fmaf(wv.y, xv.x, acc[1].x); acc[1].y = fmaf(wv.y, xv.y, acc[1].y);
        acc[2].x = fmaf(wv.z, xv.x, acc[2].x); acc[2].y = fmaf(wv.z, xv.y, acc[2].y);
        acc[3].x = fmaf(wv.w, xv.x, acc[3].x); acc[3].y = fmaf(wv.w, xv.y, acc[3].y);
    }
#pragma unroll
    for (int r = 0; r < 4; ++r)
        ((float2*)(rows + (o0 + r) * N))[t] = acc[r];
}

// -------- Kernel 2: per-i mega kernel — sim(4h) + softmax + PV + outproj --------
__global__ __launch_bounds__(256) void attn_kernel(const float* __restrict__ ws,
                                                   const float* __restrict__ ind,
                                                   const float* __restrict__ b_out,
                                                   float* __restrict__ out) {
    const int i    = blockIdx.x;
    const int t    = threadIdx.x;
    const int lane = t & 63;
    const int wave = t >> 6;

    const float* rows   = ws + ROWS_F;
    const float* MhS    = ws + MHS_F;
    const float* w_outT = ws + WOUTT_F;

    const float* q  = rows;
    const float* k  = rows + DIMC * N;
    const float* v  = rows + 2 * DIMC * N;
    const float* Aq = rows + 3 * DIMC * N;
    const float* Ak = Aq + HEADS * INDC * N;

    __shared__ float qs[DIMC];
    __shared__ float aqs[HEADS * INDC];
    __shared__ float msS[HEADS * 16];
    __shared__ float ps[HEADS][N];
    __shared__ float red[HEADS][DH][64];
    __shared__ float red4[2][HEADS][4];
    __shared__ float attv[DIMC];
    __shared__ float outred[4][DIMC];

    if (t < DIMC) qs[t] = q[t * N + i];
    else if (t >= 128 && t < 128 + HEADS * INDC) aqs[t - 128] = Aq[(t - 128) * N + i];
    else if (t >= 160 && t < 160 + HEADS * 16) msS[t - 160] = MhS[t - 160];
    __syncthreads();

    // ---- phase 1: sim for all heads; thread t owns j-pair (2t, 2t+1) ----
    float2 ic[INDC];
#pragma unroll
    for (int c = 0; c < INDC; ++c)
        ic[c] = ((const float2*)(ind + (c * N + i) * N))[t];

    // shared symmetric products: 5 squares + 10 cross (order matches PC/PCC)
    float2 prod[15];
#pragma unroll
    for (int c = 0; c < INDC; ++c)
        prod[c] = make_float2(ic[c].x * ic[c].x, ic[c].y * ic[c].y);
    {
        int p = 5;
#pragma unroll
        for (int c = 0; c < INDC; ++c)
#pragma unroll
            for (int cc = c + 1; cc < INDC; ++cc, ++p)
                prod[p] = make_float2(ic[c].x * ic[cc].x, ic[c].y * ic[cc].y);
    }

    const float2* k2  = (const float2*)k;
    const float2* Ak2 = (const float2*)Ak;
    float2 sim[HEADS];
#pragma unroll
    for (int h = 0; h < HEADS; ++h) {
        float2 qk = {0.f, 0.f};
#pragma unroll
        for (int d4 = 0; d4 < DH / 4; ++d4) {
            const float4 qv = *(const float4*)(qs + h * DH + 4 * d4);
            float2 kv;
            kv = k2[(h * DH + 4 * d4 + 0) * 256 + t];
            qk.x = fmaf(qv.x, kv.x, qk.x); qk.y = fmaf(qv.x, kv.y, qk.y);
            kv = k2[(h * DH + 4 * d4 + 1) * 256 + t];
            qk.x = fmaf(qv.y, kv.x, qk.x); qk.y = fmaf(qv.y, kv.y, qk.y);
            kv = k2[(h * DH + 4 * d4 + 2) * 256 + t];
            qk.x = fmaf(qv.z, kv.x, qk.x); qk.y = fmaf(qv.z, kv.y, qk.y);
            kv = k2[(h * DH + 4 * d4 + 3) * 256 + t];
            qk.x = fmaf(qv.w, kv.x, qk.x); qk.y = fmaf(qv.w, kv.y, qk.y);
        }
        float2 lin = {0.f, 0.f};
#pragma unroll
        for (int c = 0; c < INDC; ++c) {
            const float2 akv = Ak2[(h * INDC + c) * 256 + t];
            const float aqv = aqs[h * INDC + c];
            lin.x = fmaf(aqv + akv.x, ic[c].x, lin.x);
            lin.y = fmaf(aqv + akv.y, ic[c].y, lin.y);
        }
        float2 quad = {0.f, 0.f};
#pragma unroll
        for (int p = 0; p < 15; ++p) {
            const float sv = msS[h * 16 + p];
            quad.x = fmaf(sv, prod[p].x, quad.x);
            quad.y = fmaf(sv, prod[p].y, quad.y);
        }
        sim[h].x = SCALE * (qk.x + lin.x + quad.x);
        sim[h].y = SCALE * (qk.y + lin.y + quad.y);
    }

    // ---- softmax per head over 512 ----
#pragma unroll
    for (int h = 0; h < HEADS; ++h) {
        float m = fmaxf(sim[h].x, sim[h].y);
#pragma unroll
        for (int off = 32; off; off >>= 1) m = fmaxf(m, __shfl_down(m, off, 64));
        if (lane == 0) red4[0][h][wave] = m;
    }
    __syncthreads();
    float2 e[HEADS];
#pragma unroll
    for (int h = 0; h < HEADS; ++h) {
        const float m = fmaxf(fmaxf(red4[0][h][0], red4[0][h][1]),
                              fmaxf(red4[0][h][2], red4[0][h][3]));
        e[h].x = __expf(sim[h].x - m);
        e[h].y = __expf(sim[h].y - m);
        float s = e[h].x + e[h].y;
#pragma unroll
        for (int off = 32; off; off >>= 1) s += __shfl_down(s, off, 64);
        if (lane == 0) red4[1][h][wave] = s;
    }
    __syncthreads();
#pragma unroll
    for (int h = 0; h < HEADS; ++h) {
        const float s = (red4[1][h][0] + red4[1][h][1]) + (red4[1][h][2] + red4[1][h][3]);
        const float rs = 1.f / s;
        ((float2*)&ps[h][0])[t] = make_float2(e[h].x * rs, e[h].y * rs);
    }
    __syncthreads();

    // ---- PV: wave h owns head h; 32 register accumulators per lane ----
    {
        const int h = wave;
        float acc[DH];
#pragma unroll
        for (int d = 0; d < DH; ++d) acc[d] = 0.f;
        const float2* ps2 = (const float2*)&ps[h][0];
        const float2* v2  = (const float2*)v;
        for (int s = 0; s < 4; ++s) {
            const float2 p = ps2[lane + 64 * s];
#pragma unroll
            for (int d = 0; d < DH; ++d) {
                const float2 vv = v2[(h * DH + d) * 256 + lane + 64 * s];
                acc[d] = fmaf(p.x, vv.x, fmaf(p.y, vv.y, acc[d]));
            }
        }
        // XOR-swizzled in-wave transpose reduce (conflict-free)
#pragma unroll
        for (int d = 0; d < DH; ++d) red[h][d][lane ^ d] = acc[d];
        const int d = lane & 31, half = lane >> 5;
        float s = 0.f;
#pragma unroll
        for (int kk = 0; kk < 32; ++kk) s += red[h][d][(half * 32 + kk) ^ d];
        s += __shfl_down(s, 32, 64);
        if (lane < 32) attv[h * DH + d] = s;
    }
    __syncthreads();

    // ---- fused output projection: out[:, i] = w_out @ attv + b ----
    {
        const int po = t & 63;          // float2 o-pair index
        const int quarter = t >> 6;     // 4 quarters of 32 c each
        const float2* wT2 = (const float2*)w_outT;
        float2 acc2 = {0.f, 0.f};
#pragma unroll 8
        for (int c = quarter * 32; c < quarter * 32 + 32; ++c) {
            const float av = attv[c];
            const float2 wv = wT2[c * 64 + po];
            acc2.x = fmaf(wv.x, av, acc2.x);
            acc2.y = fmaf(wv.y, av, acc2.y);
        }
        ((float2*)&outred[quarter][0])[po] = acc2;
    }
    __syncthreads();
    if (t < DIMC)
        out[t * N + i] = ((outred[0][t] + outred[1][t]) + (outred[2][t] + outred[3][t]))
                         + b_out[t];
}

extern "C" void kernel_launch(void* const* d_in, const int* in_sizes, int n_in,
                              void* d_out, int out_size, void* d_ws, size_t ws_size,
                              hipStream_t stream) {
    const float* x         = (const float*)d_in[0];  // (1,128,512)
    const float* indicator = (const float*)d_in[1];  // (1,5,512,512)
    const float* w_qkv     = (const float*)d_in[2];  // (384,128)
    const float* w_ind     = (const float*)d_in[3];  // (256,5)
    const float* w_out     = (const float*)d_in[4];  // (128,128)
    const float* b_out     = (const float*)d_in[5];  // (128,)
    float* out = (float*)d_out;                      // (1,128,512)
    float* ws  = (float*)d_ws;

    pre_kernel<<<NROW_BLK + 1, 256, 0, stream>>>(w_qkv, w_ind, x, w_out, ws);
    attn_kernel<<<N, 256, 0, stream>>>(ws, indicator, b_out, out);
}

// Round 4
// 115.024 us; speedup vs baseline: 1.2014x; 1.0205x over previous
//
#include <hip/hip_runtime.h>
#include <math.h>

#define N      512
#define DIMC   128
#define HEADS  4
#define DH     32
#define INDC   5
#define SCALE  0.1767766952966369f   // 32^-0.5

// Virtual output rows of the fused pre-GEMM: all are (row_weights) @ x
//   rows [0,384)   : qkv   (q rows 0..127, k 128..255, v 256..383)
//   rows [384,404) : Aq[(h*5+c)]  composite weight  Wq_rows . W_ind_k
//   rows [404,424) : Ak[(h*5+c)]  composite weight  Wk_rows . W_ind_q
#define QKV_ROWS 384
#define AQ_BASE  384
#define AK_BASE  404
#define TOT_ROWS 424
#define NROW_BLK (TOT_ROWS / 4)   // 106

// ws float offsets
#define ROWS_F   0
#define MHS_F    (TOT_ROWS * N)          // 64 floats: MhS[4][16] symmetrized
#define WOUTT_F  (MHS_F + 64)            // 16384 floats: w_out transposed

// ---------------- Kernel 1: fused pre-GEMM + MhS + w_out transpose ----------------
__global__ __launch_bounds__(256) void pre_kernel(const float* __restrict__ w_qkv,
                                                  const float* __restrict__ w_ind,
                                                  const float* __restrict__ x,
                                                  const float* __restrict__ w_out,
                                                  float* __restrict__ ws) {
    const int bx = blockIdx.x;
    const int t  = threadIdx.x;
    float* rows   = ws + ROWS_F;
    float* MhS    = ws + MHS_F;
    float* w_outT = ws + WOUTT_F;

    if (bx == NROW_BLK) {
        if (blockIdx.y != 0) return;
        // --- M[h,c,cc] = sum_d w_ind_q[h,d,c] * w_ind_k[h,d,cc], then symmetrize ---
        __shared__ float mraw[HEADS * INDC * INDC];
        if (t < HEADS * INDC * INDC) {
            const int h = t / 25, c = (t / 5) % 5, cc = t % 5;
            float acc = 0.f;
            for (int d = 0; d < DH; ++d)
                acc = fmaf(w_ind[(h * DH + d) * INDC + c],
                           w_ind[(DIMC + h * DH + d) * INDC + cc], acc);
            mraw[t] = acc;
        }
        __syncthreads();
        if (t < 64) {
            const int h = t >> 4, idx = t & 15;
            const int PC[10]  = {0, 0, 0, 0, 1, 1, 1, 2, 2, 3};
            const int PCC[10] = {1, 2, 3, 4, 2, 3, 4, 3, 4, 4};
            float s = 0.f;
            if (idx < 5) {
                s = mraw[h * 25 + idx * 5 + idx];
            } else if (idx < 15) {
                const int c = PC[idx - 5], cc = PCC[idx - 5];
                s = mraw[h * 25 + c * 5 + cc] + mraw[h * 25 + cc * 5 + c];
            }
            MhS[h * 16 + idx] = s;
        }
        // --- transpose w_out (128x128) so the fused outproj reads coalesced ---
        for (int idx = t; idx < DIMC * DIMC; idx += 256) {
            const int o = idx >> 7, c = idx & 127;
            w_outT[c * DIMC + o] = w_out[idx];
        }
        return;
    }

    // --- 4 virtual rows per block, c-major float4 layout in LDS ---
    __shared__ float ws2[4 * DIMC];   // ws2[c*4 + r]
    const int o0 = bx * 4;
    for (int idx = t; idx < 4 * DIMC; idx += 256) {
        const int r = idx & 3, m = idx >> 2;
        const int row = o0 + r;
        float val;
        if (row < QKV_ROWS) {
            val = w_qkv[row * DIMC + m];
        } else if (row < AK_BASE) {              // Aq composite: q-rows . W_ind_k
            const int rr = row - AQ_BASE, h = rr / INDC, c = rr % INDC;
            float acc = 0.f;
            for (int d = 0; d < DH; ++d)
                acc = fmaf(w_qkv[(h * DH + d) * DIMC + m],
                           w_ind[(DIMC + h * DH + d) * INDC + c], acc);
            val = acc;
        } else {                                  // Ak composite: k-rows . W_ind_q
            const int rr = row - AK_BASE, h = rr / INDC, c = rr % INDC;
            float acc = 0.f;
            for (int d = 0; d < DH; ++d)
                acc = fmaf(w_qkv[(DIMC + h * DH + d) * DIMC + m],
                           w_ind[(h * DH + d) * INDC + c], acc);
            val = acc;
        }
        ws2[m * 4 + r] = val;
    }
    __syncthreads();

    const int i = blockIdx.y * 256 + t;   // i-split halves per-block x traffic
    float acc[4] = {0.f, 0.f, 0.f, 0.f};
#pragma unroll 8
    for (int c = 0; c < DIMC; ++c) {
        const float xv = x[c * N + i];
        const float4 wv = *(const float4*)(ws2 + c * 4);
        acc[0] = fmaf(wv.x, xv, acc[0]);
        acc[1] = fmaf(wv.y, xv, acc[1]);
        acc[2] = fmaf(wv.z, xv, acc[2]);
        acc[3] = fmaf(wv.w, xv, acc[3]);
    }
#pragma unroll
    for (int r = 0; r < 4; ++r) rows[(o0 + r) * N + i] = acc[r];
}

// -- Kernel 2: per-i-pair mega kernel — sim(4h x 2i) + softmax + PV + outproj --
// i-tile of 2: every K/V/Ak/w_out load is shared across both query columns.
__global__ __launch_bounds__(256) void attn_kernel(const float* __restrict__ ws,
                                                   const float* __restrict__ ind,
                                                   const float* __restrict__ b_out,
                                                   float* __restrict__ out) {
    const int i0   = blockIdx.x * 2;
    const int t    = threadIdx.x;
    const int lane = t & 63;
    const int wave = t >> 6;

    const float* rows   = ws + ROWS_F;
    const float* MhS    = ws + MHS_F;
    const float* w_outT = ws + WOUTT_F;

    const float* q  = rows;
    const float* k  = rows + DIMC * N;
    const float* v  = rows + 2 * DIMC * N;
    const float* Aq = rows + 3 * DIMC * N;
    const float* Ak = Aq + HEADS * INDC * N;

    __shared__ float qs[2][DIMC];
    __shared__ float aqs[2][HEADS * INDC];
    __shared__ float msS[HEADS * 16];
    __shared__ float ps[HEADS][2][N];       // 16 KB
    __shared__ float red[HEADS][DH][64];    // 32 KB (reused for both i)
    __shared__ float red4[2][HEADS][2][4];
    __shared__ float attv[2][DIMC];
    __shared__ float outred[4][2][DIMC];    // 4 KB

    if (t < DIMC) qs[0][t] = q[t * N + i0];
    else          qs[1][t - DIMC] = q[(t - DIMC) * N + i0 + 1];
    if (t < 2 * HEADS * INDC) {
        const int ii = t / (HEADS * INDC), r = t % (HEADS * INDC);
        aqs[ii][r] = Aq[r * N + i0 + ii];
    } else if (t < 2 * HEADS * INDC + 64) {
        msS[t - 2 * HEADS * INDC] = MhS[t - 2 * HEADS * INDC];
    }
    __syncthreads();

    // ---- phase 1: sim for all heads, both i; thread t owns j-pair (2t,2t+1) ----
    float2 ic0[INDC], ic1[INDC];
#pragma unroll
    for (int c = 0; c < INDC; ++c) {
        ic0[c] = ((const float2*)(ind + (c * N + i0) * N))[t];
        ic1[c] = ((const float2*)(ind + (c * N + i0 + 1) * N))[t];
    }
    // shared symmetric products: 5 squares + 10 cross (order matches PC/PCC)
    float2 prod0[15], prod1[15];
#pragma unroll
    for (int c = 0; c < INDC; ++c) {
        prod0[c] = make_float2(ic0[c].x * ic0[c].x, ic0[c].y * ic0[c].y);
        prod1[c] = make_float2(ic1[c].x * ic1[c].x, ic1[c].y * ic1[c].y);
    }
    {
        int p = 5;
#pragma unroll
        for (int c = 0; c < INDC; ++c)
#pragma unroll
            for (int cc = c + 1; cc < INDC; ++cc, ++p) {
                prod0[p] = make_float2(ic0[c].x * ic0[cc].x, ic0[c].y * ic0[cc].y);
                prod1[p] = make_float2(ic1[c].x * ic1[cc].x, ic1[c].y * ic1[cc].y);
            }
    }

    const float2* k2  = (const float2*)k;
    const float2* Ak2 = (const float2*)Ak;
    float2 sim0[HEADS], sim1[HEADS];
#pragma unroll
    for (int h = 0; h < HEADS; ++h) {
        float2 qk0 = {0.f, 0.f}, qk1 = {0.f, 0.f};
#pragma unroll
        for (int d = 0; d < DH; ++d) {
            const float2 kv = k2[(h * DH + d) * 256 + t];     // shared load
            const float q0 = qs[0][h * DH + d], q1 = qs[1][h * DH + d];
            qk0.x = fmaf(q0, kv.x, qk0.x); qk0.y = fmaf(q0, kv.y, qk0.y);
            qk1.x = fmaf(q1, kv.x, qk1.x); qk1.y = fmaf(q1, kv.y, qk1.y);
        }
        float2 lin0 = {0.f, 0.f}, lin1 = {0.f, 0.f};
#pragma unroll
        for (int c = 0; c < INDC; ++c) {
            const float2 akv = Ak2[(h * INDC + c) * 256 + t]; // shared load
            const float a0 = aqs[0][h * INDC + c], a1 = aqs[1][h * INDC + c];
            lin0.x = fmaf(a0 + akv.x, ic0[c].x, lin0.x);
            lin0.y = fmaf(a0 + akv.y, ic0[c].y, lin0.y);
            lin1.x = fmaf(a1 + akv.x, ic1[c].x, lin1.x);
            lin1.y = fmaf(a1 + akv.y, ic1[c].y, lin1.y);
        }
        float2 qd0 = {0.f, 0.f}, qd1 = {0.f, 0.f};
#pragma unroll
        for (int p = 0; p < 15; ++p) {
            const float sv = msS[h * 16 + p];
            qd0.x = fmaf(sv, prod0[p].x, qd0.x); qd0.y = fmaf(sv, prod0[p].y, qd0.y);
            qd1.x = fmaf(sv, prod1[p].x, qd1.x); qd1.y = fmaf(sv, prod1[p].y, qd1.y);
        }
        sim0[h].x = SCALE * (qk0.x + lin0.x + qd0.x);
        sim0[h].y = SCALE * (qk0.y + lin0.y + qd0.y);
        sim1[h].x = SCALE * (qk1.x + lin1.x + qd1.x);
        sim1[h].y = SCALE * (qk1.y + lin1.y + qd1.y);
    }

    // ---- softmax per (head, i) over 512 ----
#pragma unroll
    for (int h = 0; h < HEADS; ++h) {
        float m0 = fmaxf(sim0[h].x, sim0[h].y);
        float m1 = fmaxf(sim1[h].x, sim1[h].y);
#pragma unroll
        for (int off = 32; off; off >>= 1) {
            m0 = fmaxf(m0, __shfl_down(m0, off, 64));
            m1 = fmaxf(m1, __shfl_down(m1, off, 64));
        }
        if (lane == 0) { red4[0][h][0][wave] = m0; red4[0][h][1][wave] = m1; }
    }
    __syncthreads();
    float2 e0[HEADS], e1[HEADS];
#pragma unroll
    for (int h = 0; h < HEADS; ++h) {
        const float m0 = fmaxf(fmaxf(red4[0][h][0][0], red4[0][h][0][1]),
                               fmaxf(red4[0][h][0][2], red4[0][h][0][3]));
        const float m1 = fmaxf(fmaxf(red4[0][h][1][0], red4[0][h][1][1]),
                               fmaxf(red4[0][h][1][2], red4[0][h][1][3]));
        e0[h].x = __expf(sim0[h].x - m0); e0[h].y = __expf(sim0[h].y - m0);
        e1[h].x = __expf(sim1[h].x - m1); e1[h].y = __expf(sim1[h].y - m1);
        float s0 = e0[h].x + e0[h].y, s1 = e1[h].x + e1[h].y;
#pragma unroll
        for (int off = 32; off; off >>= 1) {
            s0 += __shfl_down(s0, off, 64);
            s1 += __shfl_down(s1, off, 64);
        }
        if (lane == 0) { red4[1][h][0][wave] = s0; red4[1][h][1][wave] = s1; }
    }
    __syncthreads();
#pragma unroll
    for (int h = 0; h < HEADS; ++h) {
        const float s0 = (red4[1][h][0][0] + red4[1][h][0][1]) +
                         (red4[1][h][0][2] + red4[1][h][0][3]);
        const float s1 = (red4[1][h][1][0] + red4[1][h][1][1]) +
                         (red4[1][h][1][2] + red4[1][h][1][3]);
        const float r0 = 1.f / s0, r1 = 1.f / s1;
        ((float2*)&ps[h][0][0])[t] = make_float2(e0[h].x * r0, e0[h].y * r0);
        ((float2*)&ps[h][1][0])[t] = make_float2(e1[h].x * r1, e1[h].y * r1);
    }
    __syncthreads();

    // ---- PV: wave h owns head h, both i; V loads shared ----
    {
        const int h = wave;
        float acc0[DH], acc1[DH];
#pragma unroll
        for (int d = 0; d < DH; ++d) { acc0[d] = 0.f; acc1[d] = 0.f; }
        const float2* ps0 = (const float2*)&ps[h][0][0];
        const float2* ps1 = (const float2*)&ps[h][1][0];
        const float2* v2  = (const float2*)v;
        for (int s = 0; s < 4; ++s) {
            const float2 p0 = ps0[lane + 64 * s];
            const float2 p1 = ps1[lane + 64 * s];
#pragma unroll
            for (int d = 0; d < DH; ++d) {
                const float2 vv = v2[(h * DH + d) * 256 + lane + 64 * s];
                acc0[d] = fmaf(p0.x, vv.x, fmaf(p0.y, vv.y, acc0[d]));
                acc1[d] = fmaf(p1.x, vv.x, fmaf(p1.y, vv.y, acc1[d]));
            }
        }
        // XOR-swizzled in-wave transpose reduce (conflict-free), i0 then i1
        const int d = lane & 31, half = lane >> 5;
#pragma unroll
        for (int dd = 0; dd < DH; ++dd) red[h][dd][lane ^ dd] = acc0[dd];
        float s = 0.f;
#pragma unroll
        for (int kk = 0; kk < 32; ++kk) s += red[h][d][(half * 32 + kk) ^ d];
        s += __shfl_down(s, 32, 64);
        if (lane < 32) attv[0][h * DH + d] = s;
#pragma unroll
        for (int dd = 0; dd < DH; ++dd) red[h][dd][lane ^ dd] = acc1[dd];
        s = 0.f;
#pragma unroll
        for (int kk = 0; kk < 32; ++kk) s += red[h][d][(half * 32 + kk) ^ d];
        s += __shfl_down(s, 32, 64);
        if (lane < 32) attv[1][h * DH + d] = s;
    }
    __syncthreads();

    // ---- fused output projection: out[:, i0+ii] = w_out @ attv[ii] + b ----
    {
        const int po = t & 63;          // float2 o-pair index
        const int quarter = t >> 6;     // 4 quarters of 32 c each
        const float2* wT2 = (const float2*)w_outT;
        float2 a0 = {0.f, 0.f}, a1 = {0.f, 0.f};
#pragma unroll 8
        for (int c = quarter * 32; c < quarter * 32 + 32; ++c) {
            const float2 wv = wT2[c * 64 + po];                // shared load
            const float av0 = attv[0][c], av1 = attv[1][c];
            a0.x = fmaf(wv.x, av0, a0.x); a0.y = fmaf(wv.y, av0, a0.y);
            a1.x = fmaf(wv.x, av1, a1.x); a1.y = fmaf(wv.y, av1, a1.y);
        }
        ((float2*)&outred[quarter][0][0])[po] = a0;
        ((float2*)&outred[quarter][1][0])[po] = a1;
    }
    __syncthreads();
    {
        const int o = t & 127, ii = t >> 7;
        out[o * N + i0 + ii] = ((outred[0][ii][o] + outred[1][ii][o]) +
                                (outred[2][ii][o] + outred[3][ii][o])) + b_out[o];
    }
}

extern "C" void kernel_launch(void* const* d_in, const int* in_sizes, int n_in,
                              void* d_out, int out_size, void* d_ws, size_t ws_size,
                              hipStream_t stream) {
    const float* x         = (const float*)d_in[0];  // (1,128,512)
    const float* indicator = (const float*)d_in[1];  // (1,5,512,512)
    const float* w_qkv     = (const float*)d_in[2];  // (384,128)
    const float* w_ind     = (const float*)d_in[3];  // (256,5)
    const float* w_out     = (const float*)d_in[4];  // (128,128)
    const float* b_out     = (const float*)d_in[5];  // (128,)
    float* out = (float*)d_out;                      // (1,128,512)
    float* ws  = (float*)d_ws;

    pre_kernel<<<dim3(NROW_BLK + 1, 2), 256, 0, stream>>>(w_qkv, w_ind, x, w_out, ws);
    attn_kernel<<<N / 2, 256, 0, stream>>>(ws, indicator, b_out, out);
}

// Round 5
// 101.385 us; speedup vs baseline: 1.3630x; 1.1345x over previous
//
#include <hip/hip_runtime.h>
#include <hip/hip_fp16.h>
#include <math.h>

#define N      512
#define DIMC   128
#define HEADS  4
#define DH     32
#define INDC   5
#define SCALE  0.1767766952966369f   // 32^-0.5

// Virtual output rows of the fused pre-GEMM: all are (row_weights) @ x
//   rows [0,384)   : qkv   (q rows 0..127, k 128..255, v 256..383)
//   rows [384,404) : Aq[(h*5+c)]  composite weight  Wq_rows . W_ind_k
//   rows [404,424) : Ak[(h*5+c)]  composite weight  Wk_rows . W_ind_q
// rows are stored FP16 (halves attn's L2-side K/V traffic; error << threshold)
#define QKV_ROWS 384
#define AQ_BASE  384
#define AK_BASE  404
#define TOT_ROWS 424
#define NROW_BLK (TOT_ROWS / 4)   // 106

// ws layout: [rows fp16: TOT_ROWS*N halves][MhS 64 f32][w_outT 16384 f32]
#define MHS_F    (TOT_ROWS * N / 2)      // float offset after fp16 rows
#define WOUTT_F  (MHS_F + 64)

// ---------------- Kernel 1: fused pre-GEMM + MhS + w_out transpose ----------------
__global__ __launch_bounds__(256) void pre_kernel(const float* __restrict__ w_qkv,
                                                  const float* __restrict__ w_ind,
                                                  const float* __restrict__ x,
                                                  const float* __restrict__ w_out,
                                                  float* __restrict__ ws) {
    const int bx = blockIdx.x;
    const int t  = threadIdx.x;
    __half* rows  = (__half*)ws;
    float* MhS    = ws + MHS_F;
    float* w_outT = ws + WOUTT_F;

    if (bx == NROW_BLK) {
        if (blockIdx.y != 0) return;
        // --- M[h,c,cc] = sum_d w_ind_q[h,d,c] * w_ind_k[h,d,cc], then symmetrize ---
        __shared__ float mraw[HEADS * INDC * INDC];
        if (t < HEADS * INDC * INDC) {
            const int h = t / 25, c = (t / 5) % 5, cc = t % 5;
            float acc = 0.f;
            for (int d = 0; d < DH; ++d)
                acc = fmaf(w_ind[(h * DH + d) * INDC + c],
                           w_ind[(DIMC + h * DH + d) * INDC + cc], acc);
            mraw[t] = acc;
        }
        __syncthreads();
        if (t < 64) {
            const int h = t >> 4, idx = t & 15;
            const int PC[10]  = {0, 0, 0, 0, 1, 1, 1, 2, 2, 3};
            const int PCC[10] = {1, 2, 3, 4, 2, 3, 4, 3, 4, 4};
            float s = 0.f;
            if (idx < 5) {
                s = mraw[h * 25 + idx * 5 + idx];
            } else if (idx < 15) {
                const int c = PC[idx - 5], cc = PCC[idx - 5];
                s = mraw[h * 25 + c * 5 + cc] + mraw[h * 25 + cc * 5 + c];
            }
            MhS[h * 16 + idx] = s;
        }
        // --- transpose w_out (128x128) so the fused outproj reads coalesced ---
        for (int idx = t; idx < DIMC * DIMC; idx += 256) {
            const int o = idx >> 7, c = idx & 127;
            w_outT[c * DIMC + o] = w_out[idx];
        }
        return;
    }

    // --- 4 virtual rows per block, c-major float4 layout in LDS ---
    __shared__ float ws2[4 * DIMC];   // ws2[c*4 + r]
    const int o0 = bx * 4;
    for (int idx = t; idx < 4 * DIMC; idx += 256) {
        const int r = idx & 3, m = idx >> 2;
        const int row = o0 + r;
        float val;
        if (row < QKV_ROWS) {
            val = w_qkv[row * DIMC + m];
        } else if (row < AK_BASE) {              // Aq composite: q-rows . W_ind_k
            const int rr = row - AQ_BASE, h = rr / INDC, c = rr % INDC;
            float acc = 0.f;
            for (int d = 0; d < DH; ++d)
                acc = fmaf(w_qkv[(h * DH + d) * DIMC + m],
                           w_ind[(DIMC + h * DH + d) * INDC + c], acc);
            val = acc;
        } else {                                  // Ak composite: k-rows . W_ind_q
            const int rr = row - AK_BASE, h = rr / INDC, c = rr % INDC;
            float acc = 0.f;
            for (int d = 0; d < DH; ++d)
                acc = fmaf(w_qkv[(DIMC + h * DH + d) * DIMC + m],
                           w_ind[(h * DH + d) * INDC + c], acc);
            val = acc;
        }
        ws2[m * 4 + r] = val;
    }
    __syncthreads();

    const int i = blockIdx.y * 256 + t;   // i-split halves per-block x traffic
    float acc[4] = {0.f, 0.f, 0.f, 0.f};
#pragma unroll 8
    for (int c = 0; c < DIMC; ++c) {
        const float xv = x[c * N + i];
        const float4 wv = *(const float4*)(ws2 + c * 4);
        acc[0] = fmaf(wv.x, xv, acc[0]);
        acc[1] = fmaf(wv.y, xv, acc[1]);
        acc[2] = fmaf(wv.z, xv, acc[2]);
        acc[3] = fmaf(wv.w, xv, acc[3]);
    }
#pragma unroll
    for (int r = 0; r < 4; ++r) rows[(o0 + r) * N + i] = __float2half(acc[r]);
}

// -- Kernel 2: per-i-pair mega kernel — sim(4h x 2i) + softmax + PV + outproj --
// i-tile of 2: every K/V/Ak/w_out load is shared across both query columns.
__global__ __launch_bounds__(256) void attn_kernel(const float* __restrict__ ws,
                                                   const float* __restrict__ ind,
                                                   const float* __restrict__ b_out,
                                                   float* __restrict__ out) {
    const int i0   = blockIdx.x * 2;
    const int t    = threadIdx.x;
    const int lane = t & 63;
    const int wave = t >> 6;

    const __half* rows  = (const __half*)ws;
    const float* MhS    = ws + MHS_F;
    const float* w_outT = ws + WOUTT_F;

    const __half* q  = rows;
    const __half* Aq = rows + 3 * DIMC * N;

    __shared__ float qs[2][DIMC];
    __shared__ float aqs[2][HEADS * INDC];
    __shared__ float msS[HEADS * 16];
    __shared__ float ps[HEADS][2][N];       // 16 KB
    __shared__ float red[HEADS][DH][64];    // 32 KB (reused for both i)
    __shared__ float red4[2][HEADS][2][4];
    __shared__ float attv[2][DIMC];
    __shared__ float outred[4][2][DIMC];    // 4 KB

    if (t < DIMC) qs[0][t] = __half2float(q[t * N + i0]);
    else          qs[1][t - DIMC] = __half2float(q[(t - DIMC) * N + i0 + 1]);
    if (t < 2 * HEADS * INDC) {
        const int ii = t / (HEADS * INDC), r = t % (HEADS * INDC);
        aqs[ii][r] = __half2float(Aq[r * N + i0 + ii]);
    } else if (t < 2 * HEADS * INDC + 64) {
        msS[t - 2 * HEADS * INDC] = MhS[t - 2 * HEADS * INDC];
    }
    __syncthreads();

    // ---- phase 1: sim for all heads, both i; thread t owns j-pair (2t,2t+1) ----
    float2 ic0[INDC], ic1[INDC];
#pragma unroll
    for (int c = 0; c < INDC; ++c) {
        ic0[c] = ((const float2*)(ind + (c * N + i0) * N))[t];
        ic1[c] = ((const float2*)(ind + (c * N + i0 + 1) * N))[t];
    }
    // shared symmetric products: 5 squares + 10 cross (order matches PC/PCC)
    float2 prod0[15], prod1[15];
#pragma unroll
    for (int c = 0; c < INDC; ++c) {
        prod0[c] = make_float2(ic0[c].x * ic0[c].x, ic0[c].y * ic0[c].y);
        prod1[c] = make_float2(ic1[c].x * ic1[c].x, ic1[c].y * ic1[c].y);
    }
    {
        int p = 5;
#pragma unroll
        for (int c = 0; c < INDC; ++c)
#pragma unroll
            for (int cc = c + 1; cc < INDC; ++cc, ++p) {
                prod0[p] = make_float2(ic0[c].x * ic0[cc].x, ic0[c].y * ic0[cc].y);
                prod1[p] = make_float2(ic1[c].x * ic1[cc].x, ic1[c].y * ic1[cc].y);
            }
    }

    const __half2* k2  = (const __half2*)(rows + DIMC * N);
    const __half2* Ak2 = (const __half2*)(rows + (3 * DIMC + HEADS * INDC) * N);
    float2 sim0[HEADS], sim1[HEADS];
#pragma unroll
    for (int h = 0; h < HEADS; ++h) {
        float2 qk0 = {0.f, 0.f}, qk1 = {0.f, 0.f};
#pragma unroll
        for (int d = 0; d < DH; ++d) {
            const float2 kv = __half22float2(k2[(h * DH + d) * 256 + t]); // shared
            const float q0 = qs[0][h * DH + d], q1 = qs[1][h * DH + d];
            qk0.x = fmaf(q0, kv.x, qk0.x); qk0.y = fmaf(q0, kv.y, qk0.y);
            qk1.x = fmaf(q1, kv.x, qk1.x); qk1.y = fmaf(q1, kv.y, qk1.y);
        }
        float2 lin0 = {0.f, 0.f}, lin1 = {0.f, 0.f};
#pragma unroll
        for (int c = 0; c < INDC; ++c) {
            const float2 akv = __half22float2(Ak2[(h * INDC + c) * 256 + t]);
            const float a0 = aqs[0][h * INDC + c], a1 = aqs[1][h * INDC + c];
            lin0.x = fmaf(a0 + akv.x, ic0[c].x, lin0.x);
            lin0.y = fmaf(a0 + akv.y, ic0[c].y, lin0.y);
            lin1.x = fmaf(a1 + akv.x, ic1[c].x, lin1.x);
            lin1.y = fmaf(a1 + akv.y, ic1[c].y, lin1.y);
        }
        float2 qd0 = {0.f, 0.f}, qd1 = {0.f, 0.f};
#pragma unroll
        for (int p = 0; p < 15; ++p) {
            const float sv = msS[h * 16 + p];
            qd0.x = fmaf(sv, prod0[p].x, qd0.x); qd0.y = fmaf(sv, prod0[p].y, qd0.y);
            qd1.x = fmaf(sv, prod1[p].x, qd1.x); qd1.y = fmaf(sv, prod1[p].y, qd1.y);
        }
        sim0[h].x = SCALE * (qk0.x + lin0.x + qd0.x);
        sim0[h].y = SCALE * (qk0.y + lin0.y + qd0.y);
        sim1[h].x = SCALE * (qk1.x + lin1.x + qd1.x);
        sim1[h].y = SCALE * (qk1.y + lin1.y + qd1.y);
    }

    // ---- softmax per (head, i) over 512 ----
#pragma unroll
    for (int h = 0; h < HEADS; ++h) {
        float m0 = fmaxf(sim0[h].x, sim0[h].y);
        float m1 = fmaxf(sim1[h].x, sim1[h].y);
#pragma unroll
        for (int off = 32; off; off >>= 1) {
            m0 = fmaxf(m0, __shfl_down(m0, off, 64));
            m1 = fmaxf(m1, __shfl_down(m1, off, 64));
        }
        if (lane == 0) { red4[0][h][0][wave] = m0; red4[0][h][1][wave] = m1; }
    }
    __syncthreads();
    float2 e0[HEADS], e1[HEADS];
#pragma unroll
    for (int h = 0; h < HEADS; ++h) {
        const float m0 = fmaxf(fmaxf(red4[0][h][0][0], red4[0][h][0][1]),
                               fmaxf(red4[0][h][0][2], red4[0][h][0][3]));
        const float m1 = fmaxf(fmaxf(red4[0][h][1][0], red4[0][h][1][1]),
                               fmaxf(red4[0][h][1][2], red4[0][h][1][3]));
        e0[h].x = __expf(sim0[h].x - m0); e0[h].y = __expf(sim0[h].y - m0);
        e1[h].x = __expf(sim1[h].x - m1); e1[h].y = __expf(sim1[h].y - m1);
        float s0 = e0[h].x + e0[h].y, s1 = e1[h].x + e1[h].y;
#pragma unroll
        for (int off = 32; off; off >>= 1) {
            s0 += __shfl_down(s0, off, 64);
            s1 += __shfl_down(s1, off, 64);
        }
        if (lane == 0) { red4[1][h][0][wave] = s0; red4[1][h][1][wave] = s1; }
    }
    __syncthreads();
#pragma unroll
    for (int h = 0; h < HEADS; ++h) {
        const float s0 = (red4[1][h][0][0] + red4[1][h][0][1]) +
                         (red4[1][h][0][2] + red4[1][h][0][3]);
        const float s1 = (red4[1][h][1][0] + red4[1][h][1][1]) +
                         (red4[1][h][1][2] + red4[1][h][1][3]);
        const float r0 = 1.f / s0, r1 = 1.f / s1;
        ((float2*)&ps[h][0][0])[t] = make_float2(e0[h].x * r0, e0[h].y * r0);
        ((float2*)&ps[h][1][0])[t] = make_float2(e1[h].x * r1, e1[h].y * r1);
    }
    __syncthreads();

    // ---- PV: wave h owns head h, both i; V loads shared ----
    {
        const int h = wave;
        float acc0[DH], acc1[DH];
#pragma unroll
        for (int d = 0; d < DH; ++d) { acc0[d] = 0.f; acc1[d] = 0.f; }
        const float2* ps0 = (const float2*)&ps[h][0][0];
        const float2* ps1 = (const float2*)&ps[h][1][0];
        const __half2* v2 = (const __half2*)(rows + 2 * DIMC * N);
        for (int s = 0; s < 4; ++s) {
            const float2 p0 = ps0[lane + 64 * s];
            const float2 p1 = ps1[lane + 64 * s];
#pragma unroll
            for (int d = 0; d < DH; ++d) {
                const float2 vv = __half22float2(v2[(h * DH + d) * 256 + lane + 64 * s]);
                acc0[d] = fmaf(p0.x, vv.x, fmaf(p0.y, vv.y, acc0[d]));
                acc1[d] = fmaf(p1.x, vv.x, fmaf(p1.y, vv.y, acc1[d]));
            }
        }
        // XOR-swizzled in-wave transpose reduce (conflict-free), i0 then i1
        const int d = lane & 31, half = lane >> 5;
#pragma unroll
        for (int dd = 0; dd < DH; ++dd) red[h][dd][lane ^ dd] = acc0[dd];
        float s = 0.f;
#pragma unroll
        for (int kk = 0; kk < 32; ++kk) s += red[h][d][(half * 32 + kk) ^ d];
        s += __shfl_down(s, 32, 64);
        if (lane < 32) attv[0][h * DH + d] = s;
#pragma unroll
        for (int dd = 0; dd < DH; ++dd) red[h][dd][lane ^ dd] = acc1[dd];
        s = 0.f;
#pragma unroll
        for (int kk = 0; kk < 32; ++kk) s += red[h][d][(half * 32 + kk) ^ d];
        s += __shfl_down(s, 32, 64);
        if (lane < 32) attv[1][h * DH + d] = s;
    }
    __syncthreads();

    // ---- fused output projection: out[:, i0+ii] = w_out @ attv[ii] + b ----
    {
        const int po = t & 63;          // float2 o-pair index
        const int quarter = t >> 6;     // 4 quarters of 32 c each
        const float2* wT2 = (const float2*)w_outT;
        float2 a0 = {0.f, 0.f}, a1 = {0.f, 0.f};
#pragma unroll 8
        for (int c = quarter * 32; c < quarter * 32 + 32; ++c) {
            const float2 wv = wT2[c * 64 + po];                // shared load
            const float av0 = attv[0][c], av1 = attv[1][c];
            a0.x = fmaf(wv.x, av0, a0.x); a0.y = fmaf(wv.y, av0, a0.y);
            a1.x = fmaf(wv.x, av1, a1.x); a1.y = fmaf(wv.y, av1, a1.y);
        }
        ((float2*)&outred[quarter][0][0])[po] = a0;
        ((float2*)&outred[quarter][1][0])[po] = a1;
    }
    __syncthreads();
    {
        const int o = t & 127, ii = t >> 7;
        out[o * N + i0 + ii] = ((outred[0][ii][o] + outred[1][ii][o]) +
                                (outred[2][ii][o] + outred[3][ii][o])) + b_out[o];
    }
}

extern "C" void kernel_launch(void* const* d_in, const int* in_sizes, int n_in,
                              void* d_out, int out_size, void* d_ws, size_t ws_size,
                              hipStream_t stream) {
    const float* x         = (const float*)d_in[0];  // (1,128,512)
    const float* indicator = (const float*)d_in[1];  // (1,5,512,512)
    const float* w_qkv     = (const float*)d_in[2];  // (384,128)
    const float* w_ind     = (const float*)d_in[3];  // (256,5)
    const float* w_out     = (const float*)d_in[4];  // (128,128)
    const float* b_out     = (const float*)d_in[5];  // (128,)
    float* out = (float*)d_out;                      // (1,128,512)
    float* ws  = (float*)d_ws;

    pre_kernel<<<dim3(NROW_BLK + 1, 2), 256, 0, stream>>>(w_qkv, w_ind, x, w_out, ws);
    attn_kernel<<<N / 2, 256, 0, stream>>>(ws, indicator, b_out, out);
}